// Round 1
// baseline (863.551 us; speedup 1.0000x reference)
//
#include <hip/hip_runtime.h>
#include <hip/hip_bf16.h>

// Problem constants (from reference)
#define BATCH 32
#define HID 1024
#define NH 16
#define HD 64
#define BS 16
#define MAX_KV 2048
#define BPS 128            // blocks per seq
#define NUM_BLOCKS 4096
#define SCALE 0.125f       // HD^-0.5

// ---------------------------------------------------------------------------
// Kernel 1: q projection. q[b, col] = hs[b,:] . w_attn[:, col] + b_attn[col]
// col in [0,1024) (only the q slice of the 3H-wide c_attn is needed).
// grid (B, 16) x 64 threads; each lane one output column.
// ---------------------------------------------------------------------------
__global__ __launch_bounds__(64) void qproj_kernel(
    const float* __restrict__ hs,      // [B, HID]
    const float* __restrict__ w_attn,  // [HID, 3*HID]
    const float* __restrict__ b_attn,  // [3*HID]
    float* __restrict__ q)             // [B, HID] (== [B, NH, HD])
{
    const int b = blockIdx.x;
    const int col = blockIdx.y * 64 + threadIdx.x;
    __shared__ float s_hs[HID];
    for (int i = threadIdx.x; i < HID; i += 64) s_hs[i] = hs[b * HID + i];
    __syncthreads();
    float acc = b_attn[col];
    const float* wp = w_attn + col;
    #pragma unroll 8
    for (int k = 0; k < HID; ++k) {
        acc += s_hs[k] * wp[(size_t)k * (3 * HID)];
    }
    q[b * HID + col] = acc;
}

// ---------------------------------------------------------------------------
// Kernel 2: paged attention decode. One 256-thread block per (head, batch).
// Lane layout: pos_sub = lane/16 (4 positions per wave), d4 = lane%16
// (16 float4 = 64 dims). K/V vectors (256 B) are read as coalesced float4s.
// ---------------------------------------------------------------------------
__global__ __launch_bounds__(256) void attn_kernel(
    const float* __restrict__ q,           // [B, NH, HD]
    const float* __restrict__ kv,          // [2, NUM_BLOCKS, BS, NH, HD]
    const int* __restrict__ block_tables,  // [B, BPS]
    const int* __restrict__ seq_lens,      // [B]
    float* __restrict__ attn_out)          // [B, NH*HD]
{
    const int h = blockIdx.x;    // 0..15
    const int b = blockIdx.y;    // 0..31
    const int tid = threadIdx.x;
    const int wave = tid >> 6;
    const int lane = tid & 63;
    const int pos_sub = lane >> 4;   // 0..3
    const int d4 = lane & 15;        // 0..15

    __shared__ float s_scores[MAX_KV];   // 8 KB
    __shared__ int   s_bt[BPS];
    __shared__ float s_red[4];
    __shared__ float s_part[4 * HD];

    const int n = seq_lens[b];
    for (int i = tid; i < BPS; i += 256) s_bt[i] = block_tables[b * BPS + i];

    const float4 qv = *reinterpret_cast<const float4*>(
        q + (size_t)(b * NH + h) * HD + d4 * 4);
    __syncthreads();

    const size_t v_off = (size_t)NUM_BLOCKS * BS * NH * HD;

    // ---- Phase 1: scores = SCALE * q.K ----
    for (int base = wave * 4; base < n; base += 16) {
        const int p = base + pos_sub;
        float partial = 0.f;
        if (p < n) {
            const int phys = s_bt[p >> 4];
            const float* kp = kv + (((size_t)phys * BS + (p & 15)) * NH + h) * HD + d4 * 4;
            const float4 k4 = *reinterpret_cast<const float4*>(kp);
            partial = qv.x * k4.x + qv.y * k4.y + qv.z * k4.z + qv.w * k4.w;
        }
        // reduce across the 16 d4 lanes
        partial += __shfl_xor(partial, 1);
        partial += __shfl_xor(partial, 2);
        partial += __shfl_xor(partial, 4);
        partial += __shfl_xor(partial, 8);
        if (p < n && d4 == 0) s_scores[p] = partial * SCALE;
    }
    __syncthreads();

    // ---- softmax over s_scores[0..n) ----
    float lmax = -1e30f;
    for (int i = tid; i < n; i += 256) lmax = fmaxf(lmax, s_scores[i]);
    #pragma unroll
    for (int m = 32; m; m >>= 1) lmax = fmaxf(lmax, __shfl_xor(lmax, m));
    if (lane == 0) s_red[wave] = lmax;
    __syncthreads();
    const float gmax = fmaxf(fmaxf(s_red[0], s_red[1]), fmaxf(s_red[2], s_red[3]));
    __syncthreads();

    float lsum = 0.f;
    for (int i = tid; i < n; i += 256) {
        const float e = __expf(s_scores[i] - gmax);
        s_scores[i] = e;
        lsum += e;
    }
    #pragma unroll
    for (int m = 32; m; m >>= 1) lsum += __shfl_xor(lsum, m);
    if (lane == 0) s_red[wave] = lsum;
    __syncthreads();
    const float inv = 1.f / (s_red[0] + s_red[1] + s_red[2] + s_red[3]);

    // ---- Phase 2: out = sum_p probs[p] * V[p] ----
    float4 acc = {0.f, 0.f, 0.f, 0.f};
    for (int base = wave * 4; base < n; base += 16) {
        const int p = base + pos_sub;
        if (p < n) {
            const int phys = s_bt[p >> 4];
            const float* vp = kv + v_off + (((size_t)phys * BS + (p & 15)) * NH + h) * HD + d4 * 4;
            const float4 v4 = *reinterpret_cast<const float4*>(vp);
            const float w = s_scores[p];
            acc.x += w * v4.x; acc.y += w * v4.y;
            acc.z += w * v4.z; acc.w += w * v4.w;
        }
    }
    // reduce across the 4 pos_sub groups (xor 16, 32)
    acc.x += __shfl_xor(acc.x, 16); acc.y += __shfl_xor(acc.y, 16);
    acc.z += __shfl_xor(acc.z, 16); acc.w += __shfl_xor(acc.w, 16);
    acc.x += __shfl_xor(acc.x, 32); acc.y += __shfl_xor(acc.y, 32);
    acc.z += __shfl_xor(acc.z, 32); acc.w += __shfl_xor(acc.w, 32);
    if (pos_sub == 0) {
        s_part[wave * HD + d4 * 4 + 0] = acc.x;
        s_part[wave * HD + d4 * 4 + 1] = acc.y;
        s_part[wave * HD + d4 * 4 + 2] = acc.z;
        s_part[wave * HD + d4 * 4 + 3] = acc.w;
    }
    __syncthreads();
    if (tid < HD) {
        const float o = (s_part[tid] + s_part[HD + tid] +
                         s_part[2 * HD + tid] + s_part[3 * HD + tid]) * inv;
        attn_out[(size_t)b * HID + h * HD + tid] = o;
    }
}

// ---------------------------------------------------------------------------
// Kernel 3: output projection. out[b,col] = attn[b,:] . w_proj[:,col] + b_proj[col]
// ---------------------------------------------------------------------------
__global__ __launch_bounds__(64) void proj_kernel(
    const float* __restrict__ attn,    // [B, HID]
    const float* __restrict__ w_proj,  // [HID, HID]
    const float* __restrict__ b_proj,  // [HID]
    float* __restrict__ out)           // [B, HID]
{
    const int b = blockIdx.x;
    const int col = blockIdx.y * 64 + threadIdx.x;
    __shared__ float s_a[HID];
    for (int i = threadIdx.x; i < HID; i += 64) s_a[i] = attn[b * HID + i];
    __syncthreads();
    float acc = b_proj[col];
    #pragma unroll 8
    for (int k = 0; k < HID; ++k) {
        acc += s_a[k] * w_proj[(size_t)k * HID + col];
    }
    out[b * HID + col] = acc;
}

extern "C" void kernel_launch(void* const* d_in, const int* in_sizes, int n_in,
                              void* d_out, int out_size, void* d_ws, size_t ws_size,
                              hipStream_t stream) {
    const float* hs     = (const float*)d_in[0];
    const float* kv     = (const float*)d_in[1];
    const int*   bt     = (const int*)d_in[2];
    const int*   sl     = (const int*)d_in[3];
    const float* w_attn = (const float*)d_in[4];
    const float* b_attn = (const float*)d_in[5];
    const float* w_proj = (const float*)d_in[6];
    const float* b_proj = (const float*)d_in[7];
    float* out = (float*)d_out;

    float* q    = (float*)d_ws;          // [B, HID] = 128 KB
    float* attn = q + BATCH * HID;       // [B, HID] = 128 KB

    qproj_kernel<<<dim3(BATCH, HID / 64), 64, 0, stream>>>(hs, w_attn, b_attn, q);
    attn_kernel<<<dim3(NH, BATCH), 256, 0, stream>>>(q, kv, bt, sl, attn);
    proj_kernel<<<dim3(BATCH, HID / 64), 64, 0, stream>>>(attn, w_proj, b_proj, out);
}

// Round 2
// 702.275 us; speedup vs baseline: 1.2296x; 1.2296x over previous
//
#include <hip/hip_runtime.h>
#include <hip/hip_bf16.h>

// Problem constants (from reference)
#define BATCH 32
#define HID 1024
#define NH 16
#define HD 64
#define BS 16
#define MAX_KV 2048
#define BPS 128            // blocks per seq
#define NUM_BLOCKS 4096
#define SCALE 0.125f       // HD^-0.5

#define SPLITS 8
#define CHUNK 256          // MAX_KV / SPLITS
#define KSPLIT 4
#define KCHUNK (HID / KSPLIT)   // 256

// ---------------------------------------------------------------------------
// Init: write biases into q and out (harness poisons ws/out with 0xAA).
// grid 128 x 256 covers 32*1024.
// ---------------------------------------------------------------------------
__global__ __launch_bounds__(256) void init_kernel(
    const float* __restrict__ b_attn, const float* __restrict__ b_proj,
    float* __restrict__ q, float* __restrict__ out)
{
    const int i = blockIdx.x * 256 + threadIdx.x;   // [0, 32*1024)
    const int col = i & (HID - 1);
    q[i]   = b_attn[col];   // q slice of c_attn bias
    out[i] = b_proj[col];
}

// ---------------------------------------------------------------------------
// Batched GEMV: y[b, colg*64+lane] += sum_k x[b,k] * w[k, col]  (atomicAdd)
// grid (16 col groups, KSPLIT) x 256. Each thread: 1 col, 32 batch accums.
// ---------------------------------------------------------------------------
__global__ __launch_bounds__(256) void gemv_kernel(
    const float* __restrict__ x,   // [BATCH, HID]
    const float* __restrict__ w,   // [HID, wstride]
    float* __restrict__ y,         // [BATCH, HID]
    int wstride)
{
    const int colg = blockIdx.x;
    const int kz = blockIdx.y;
    const int tid = threadIdx.x, wave = tid >> 6, lane = tid & 63;
    const int col = colg * 64 + lane;

    __shared__ float s_x[BATCH * KCHUNK];   // 32 KB
    for (int i = tid; i < BATCH * KCHUNK; i += 256) {
        const int bb = i >> 8, kk = i & (KCHUNK - 1);
        s_x[bb * KCHUNK + kk] = x[bb * HID + kz * KCHUNK + kk];
    }
    __syncthreads();

    float acc[BATCH];
    #pragma unroll
    for (int b = 0; b < BATCH; ++b) acc[b] = 0.f;

    const int kw = wave * (KCHUNK / 4);             // wave's 64-k slice
    const float* wp = w + (size_t)(kz * KCHUNK + kw) * wstride + col;
    #pragma unroll 4
    for (int j = 0; j < KCHUNK / 4; ++j) {
        const float wv = wp[(size_t)j * wstride];
        #pragma unroll
        for (int b = 0; b < BATCH; ++b)
            acc[b] += s_x[b * KCHUNK + kw + j] * wv;
    }

    // cross-wave reduce via LDS (reuse s_x), then one atomic per (b,col)
    __syncthreads();
    #pragma unroll
    for (int b = 0; b < BATCH; ++b)
        s_x[wave * 2048 + b * 64 + lane] = acc[b];
    __syncthreads();
    for (int i = tid; i < BATCH * 64; i += 256) {
        const int bb = i >> 6, cc = i & 63;
        const float v = s_x[0 * 2048 + bb * 64 + cc] + s_x[1 * 2048 + bb * 64 + cc]
                      + s_x[2 * 2048 + bb * 64 + cc] + s_x[3 * 2048 + bb * 64 + cc];
        atomicAdd(&y[bb * HID + colg * 64 + cc], v);
    }
}

// ---------------------------------------------------------------------------
// Flash-decode split attention. grid (NH, BATCH, SPLITS) x 256.
// Each block: 256-position chunk, local softmax, unnormalized partials to ws:
// part[b][h][s] = { o[HD], m, l }.
// ---------------------------------------------------------------------------
__global__ __launch_bounds__(256) void attn_split_kernel(
    const float* __restrict__ q,           // [B, NH, HD]
    const float* __restrict__ kv,          // [2, NUM_BLOCKS, BS, NH, HD]
    const int* __restrict__ block_tables,  // [B, BPS]
    const int* __restrict__ seq_lens,      // [B]
    float* __restrict__ part)              // [B, NH, SPLITS, HD+2]
{
    const int h = blockIdx.x, b = blockIdx.y, s = blockIdx.z;
    const int tid = threadIdx.x, wave = tid >> 6, lane = tid & 63;
    const int pos_sub = lane >> 4;   // 0..3
    const int d4 = lane & 15;        // 0..15

    float* my_part = part + ((size_t)(b * NH + h) * SPLITS + s) * (HD + 2);
    const int n = seq_lens[b];
    const int p0 = s * CHUNK;

    if (p0 >= n) {   // empty chunk: sentinel partial
        if (tid < HD) my_part[tid] = 0.f;
        if (tid == 0) { my_part[HD] = -1e30f; my_part[HD + 1] = 0.f; }
        return;
    }
    const int cnt = min(n - p0, CHUNK);

    __shared__ float s_sc[CHUNK];
    __shared__ int   s_bt[CHUNK / BS];
    __shared__ float s_redm[4], s_redl[4];
    __shared__ float s_part[4 * HD];

    if (tid < CHUNK / BS) s_bt[tid] = block_tables[b * BPS + p0 / BS + tid];
    const float4 qv = *reinterpret_cast<const float4*>(
        q + (size_t)(b * NH + h) * HD + d4 * 4);
    __syncthreads();

    const size_t v_off = (size_t)NUM_BLOCKS * BS * NH * HD;

    // ---- Phase 1: scores (2 positions per lane-group per iter for ILP) ----
    for (int base = wave * 8; base < cnt; base += 32) {
        const int pa = base + 2 * pos_sub;
        const int pb = pa + 1;
        float sa = 0.f, sb = 0.f;
        if (pa < cnt) {
            const float* kp = kv + (((size_t)s_bt[pa >> 4] * BS + (pa & 15)) * NH + h) * HD + d4 * 4;
            const float4 k4 = *reinterpret_cast<const float4*>(kp);
            sa = qv.x * k4.x + qv.y * k4.y + qv.z * k4.z + qv.w * k4.w;
        }
        if (pb < cnt) {
            const float* kp = kv + (((size_t)s_bt[pb >> 4] * BS + (pb & 15)) * NH + h) * HD + d4 * 4;
            const float4 k4 = *reinterpret_cast<const float4*>(kp);
            sb = qv.x * k4.x + qv.y * k4.y + qv.z * k4.z + qv.w * k4.w;
        }
        sa += __shfl_xor(sa, 1); sb += __shfl_xor(sb, 1);
        sa += __shfl_xor(sa, 2); sb += __shfl_xor(sb, 2);
        sa += __shfl_xor(sa, 4); sb += __shfl_xor(sb, 4);
        sa += __shfl_xor(sa, 8); sb += __shfl_xor(sb, 8);
        if (d4 == 0) {
            if (pa < cnt) s_sc[pa] = sa * SCALE;
            if (pb < cnt) s_sc[pb] = sb * SCALE;
        }
    }
    __syncthreads();

    // ---- local softmax over s_sc[0..cnt) — one value per thread ----
    const float v = (tid < cnt) ? s_sc[tid] : -1e30f;
    float m = v;
    #pragma unroll
    for (int msk = 32; msk; msk >>= 1) m = fmaxf(m, __shfl_xor(m, msk));
    if (lane == 0) s_redm[wave] = m;
    __syncthreads();
    m = fmaxf(fmaxf(s_redm[0], s_redm[1]), fmaxf(s_redm[2], s_redm[3]));

    const float e = (tid < cnt) ? __expf(v - m) : 0.f;
    if (tid < cnt) s_sc[tid] = e;
    float l = e;
    #pragma unroll
    for (int msk = 32; msk; msk >>= 1) l += __shfl_xor(l, msk);
    if (lane == 0) s_redl[wave] = l;
    __syncthreads();
    const float l_tot = s_redl[0] + s_redl[1] + s_redl[2] + s_redl[3];

    // ---- Phase 2: unnormalized o = sum_p e_p * V_p ----
    float4 acc = {0.f, 0.f, 0.f, 0.f};
    for (int base = wave * 8; base < cnt; base += 32) {
        const int pa = base + 2 * pos_sub;
        const int pb = pa + 1;
        if (pa < cnt) {
            const float* vp = kv + v_off + (((size_t)s_bt[pa >> 4] * BS + (pa & 15)) * NH + h) * HD + d4 * 4;
            const float4 v4 = *reinterpret_cast<const float4*>(vp);
            const float w = s_sc[pa];
            acc.x += w * v4.x; acc.y += w * v4.y; acc.z += w * v4.z; acc.w += w * v4.w;
        }
        if (pb < cnt) {
            const float* vp = kv + v_off + (((size_t)s_bt[pb >> 4] * BS + (pb & 15)) * NH + h) * HD + d4 * 4;
            const float4 v4 = *reinterpret_cast<const float4*>(vp);
            const float w = s_sc[pb];
            acc.x += w * v4.x; acc.y += w * v4.y; acc.z += w * v4.z; acc.w += w * v4.w;
        }
    }
    acc.x += __shfl_xor(acc.x, 16); acc.y += __shfl_xor(acc.y, 16);
    acc.z += __shfl_xor(acc.z, 16); acc.w += __shfl_xor(acc.w, 16);
    acc.x += __shfl_xor(acc.x, 32); acc.y += __shfl_xor(acc.y, 32);
    acc.z += __shfl_xor(acc.z, 32); acc.w += __shfl_xor(acc.w, 32);
    if (pos_sub == 0) {
        s_part[wave * HD + d4 * 4 + 0] = acc.x;
        s_part[wave * HD + d4 * 4 + 1] = acc.y;
        s_part[wave * HD + d4 * 4 + 2] = acc.z;
        s_part[wave * HD + d4 * 4 + 3] = acc.w;
    }
    __syncthreads();
    if (tid < HD) {
        my_part[tid] = s_part[tid] + s_part[HD + tid] +
                       s_part[2 * HD + tid] + s_part[3 * HD + tid];
    }
    if (tid == 0) { my_part[HD] = m; my_part[HD + 1] = l_tot; }
}

// ---------------------------------------------------------------------------
// Combine split partials: out = sum_s exp(m_s-m*) o_s / sum_s exp(m_s-m*) l_s
// grid (NH, BATCH) x 64.
// ---------------------------------------------------------------------------
__global__ __launch_bounds__(64) void attn_reduce_kernel(
    const float* __restrict__ part,        // [B, NH, SPLITS, HD+2]
    float* __restrict__ attn_out)          // [B, HID]
{
    const int h = blockIdx.x, b = blockIdx.y, d = threadIdx.x;
    const float* pp = part + (size_t)(b * NH + h) * SPLITS * (HD + 2);
    float m = -1e30f;
    #pragma unroll
    for (int s = 0; s < SPLITS; ++s) m = fmaxf(m, pp[s * (HD + 2) + HD]);
    float o = 0.f, l = 0.f;
    #pragma unroll
    for (int s = 0; s < SPLITS; ++s) {
        const float a = __expf(pp[s * (HD + 2) + HD] - m);
        o += a * pp[s * (HD + 2) + d];
        l += a * pp[s * (HD + 2) + HD + 1];
    }
    attn_out[(size_t)b * HID + h * HD + d] = o / l;
}

extern "C" void kernel_launch(void* const* d_in, const int* in_sizes, int n_in,
                              void* d_out, int out_size, void* d_ws, size_t ws_size,
                              hipStream_t stream) {
    const float* hs     = (const float*)d_in[0];
    const float* kv     = (const float*)d_in[1];
    const int*   bt     = (const int*)d_in[2];
    const int*   sl     = (const int*)d_in[3];
    const float* w_attn = (const float*)d_in[4];
    const float* b_attn = (const float*)d_in[5];
    const float* w_proj = (const float*)d_in[6];
    const float* b_proj = (const float*)d_in[7];
    float* out = (float*)d_out;

    float* q    = (float*)d_ws;                        // [B, HID]
    float* attn = q + BATCH * HID;                     // [B, HID]
    float* part = attn + BATCH * HID;                  // [B, NH, SPLITS, HD+2]

    init_kernel<<<BATCH * HID / 256, 256, 0, stream>>>(b_attn, b_proj, q, out);
    gemv_kernel<<<dim3(HID / 64, KSPLIT), 256, 0, stream>>>(hs, w_attn, q, 3 * HID);
    attn_split_kernel<<<dim3(NH, BATCH, SPLITS), 256, 0, stream>>>(q, kv, bt, sl, part);
    attn_reduce_kernel<<<dim3(NH, BATCH), 64, 0, stream>>>(part, attn);
    gemv_kernel<<<dim3(HID / 64, KSPLIT), 256, 0, stream>>>(attn, w_proj, out, HID);
}

// Round 3
// 691.482 us; speedup vs baseline: 1.2488x; 1.0156x over previous
//
#include <hip/hip_runtime.h>
#include <hip/hip_bf16.h>

// Problem constants (from reference)
#define BATCH 32
#define HID 1024
#define NH 16
#define HD 64
#define BS 16
#define MAX_KV 2048
#define BPS 128            // blocks per seq
#define NUM_BLOCKS 4096
#define SCALE 0.125f       // HD^-0.5

#define SPLITS 16
#define CHUNK 128          // MAX_KV / SPLITS
#define KSPLIT 16
#define KCHUNK (HID / KSPLIT)   // 64

// ---------------------------------------------------------------------------
// Init: write biases into q and out (harness poisons ws/out before each run).
// ---------------------------------------------------------------------------
__global__ __launch_bounds__(256) void init_kernel(
    const float* __restrict__ b_attn, const float* __restrict__ b_proj,
    float* __restrict__ q, float* __restrict__ out)
{
    const int i = blockIdx.x * 256 + threadIdx.x;   // [0, 32*1024)
    const int col = i & (HID - 1);
    q[i]   = b_attn[col];   // q slice of c_attn bias
    out[i] = b_proj[col];
}

// ---------------------------------------------------------------------------
// Batched GEMV: y[b, col] += sum_{k in kz-slice} x[b,k] * w[k, col]
// grid (16 col groups, 16 k slices) x 256. Wave w owns batches 8w..8w+7;
// each lane owns one column, 8 batch accumulators; one atomicAdd per (b,col).
// ---------------------------------------------------------------------------
__global__ __launch_bounds__(256) void gemv_kernel(
    const float* __restrict__ x,   // [BATCH, HID]
    const float* __restrict__ w,   // [HID, wstride]
    float* __restrict__ y,         // [BATCH, HID]
    int wstride)
{
    const int colg = blockIdx.x;
    const int kz = blockIdx.y;
    const int tid = threadIdx.x, wave = tid >> 6, lane = tid & 63;
    const int col = colg * 64 + lane;

    __shared__ __align__(16) float s_x[BATCH * KCHUNK];   // 8 KB, [b][k]
    for (int i = tid; i < BATCH * KCHUNK; i += 256) {
        const int bb = i >> 6, kk = i & (KCHUNK - 1);
        s_x[i] = x[bb * HID + kz * KCHUNK + kk];
    }
    __syncthreads();

    const int b0 = wave * 8;
    float acc[8];
    #pragma unroll
    for (int b = 0; b < 8; ++b) acc[b] = 0.f;

    const float4* s_x4 = reinterpret_cast<const float4*>(s_x);
    const float* wp = w + (size_t)(kz * KCHUNK) * wstride + col;
    #pragma unroll
    for (int jb = 0; jb < KCHUNK / 4; ++jb) {
        const float wv0 = wp[(size_t)(jb * 4 + 0) * wstride];
        const float wv1 = wp[(size_t)(jb * 4 + 1) * wstride];
        const float wv2 = wp[(size_t)(jb * 4 + 2) * wstride];
        const float wv3 = wp[(size_t)(jb * 4 + 3) * wstride];
        #pragma unroll
        for (int b = 0; b < 8; ++b) {
            const float4 xv = s_x4[(b0 + b) * (KCHUNK / 4) + jb];
            acc[b] += xv.x * wv0 + xv.y * wv1 + xv.z * wv2 + xv.w * wv3;
        }
    }
    #pragma unroll
    for (int b = 0; b < 8; ++b)
        atomicAdd(&y[(size_t)(b0 + b) * HID + col], acc[b]);
}

// ---------------------------------------------------------------------------
// Flash-decode split attention. grid (NH, BATCH, SPLITS) x 256.
// Each block: 128-position chunk, local softmax, unnormalized partial
// {o[HD], m, l} to ws. Empty chunks return immediately (reduce kernel
// consults seq_lens itself).
// ---------------------------------------------------------------------------
__global__ __launch_bounds__(256) void attn_split_kernel(
    const float* __restrict__ q,           // [B, NH, HD]
    const float* __restrict__ kv,          // [2, NUM_BLOCKS, BS, NH, HD]
    const int* __restrict__ block_tables,  // [B, BPS]
    const int* __restrict__ seq_lens,      // [B]
    float* __restrict__ part)              // [B, NH, SPLITS, HD+2]
{
    const int h = blockIdx.x, b = blockIdx.y, s = blockIdx.z;
    const int n = seq_lens[b];
    const int p0 = s * CHUNK;
    if (p0 >= n) return;
    const int cnt = min(n - p0, CHUNK);

    const int tid = threadIdx.x, wave = tid >> 6, lane = tid & 63;
    const int pos_sub = lane >> 4;   // 0..3
    const int d4 = lane & 15;        // 0..15

    float* my_part = part + ((size_t)(b * NH + h) * SPLITS + s) * (HD + 2);

    __shared__ float s_sc[CHUNK];
    __shared__ int   s_bt[CHUNK / BS];
    __shared__ float s_redm[4], s_redl[4];
    __shared__ float s_part[4 * HD];

    if (tid < CHUNK / BS) s_bt[tid] = block_tables[b * BPS + s * (CHUNK / BS) + tid];
    float4 qv = *reinterpret_cast<const float4*>(
        q + (size_t)(b * NH + h) * HD + d4 * 4);
    qv.x *= SCALE; qv.y *= SCALE; qv.z *= SCALE; qv.w *= SCALE;
    __syncthreads();

    const size_t v_off = (size_t)NUM_BLOCKS * BS * NH * HD;

    // ---- Phase 1: scores (4 positions per lane-group in flight) ----
    for (int base = wave * 16; base < cnt; base += 64) {
        float sc[4];
        #pragma unroll
        for (int u = 0; u < 4; ++u) {
            const int p = base + 4 * pos_sub + u;
            sc[u] = 0.f;
            if (p < cnt) {
                const float* kp = kv + (((size_t)s_bt[p >> 4] * BS + (p & 15)) * NH + h) * HD + d4 * 4;
                const float4 k4 = *reinterpret_cast<const float4*>(kp);
                sc[u] = qv.x * k4.x + qv.y * k4.y + qv.z * k4.z + qv.w * k4.w;
            }
        }
        #pragma unroll
        for (int u = 0; u < 4; ++u) {
            sc[u] += __shfl_xor(sc[u], 1);
            sc[u] += __shfl_xor(sc[u], 2);
            sc[u] += __shfl_xor(sc[u], 4);
            sc[u] += __shfl_xor(sc[u], 8);
            const int p = base + 4 * pos_sub + u;
            if (d4 == 0 && p < cnt) s_sc[p] = sc[u];
        }
    }
    __syncthreads();

    // ---- local softmax over s_sc[0..cnt) — one value per thread ----
    const float v = (tid < cnt) ? s_sc[tid] : -1e30f;
    float m = v;
    #pragma unroll
    for (int msk = 32; msk; msk >>= 1) m = fmaxf(m, __shfl_xor(m, msk));
    if (lane == 0) s_redm[wave] = m;
    __syncthreads();
    m = fmaxf(fmaxf(s_redm[0], s_redm[1]), fmaxf(s_redm[2], s_redm[3]));

    const float e = (tid < cnt) ? __expf(v - m) : 0.f;
    if (tid < cnt) s_sc[tid] = e;
    float l = e;
    #pragma unroll
    for (int msk = 32; msk; msk >>= 1) l += __shfl_xor(l, msk);
    if (lane == 0) s_redl[wave] = l;
    __syncthreads();
    const float l_tot = s_redl[0] + s_redl[1] + s_redl[2] + s_redl[3];

    // ---- Phase 2: unnormalized o = sum_p e_p * V_p ----
    float4 acc = {0.f, 0.f, 0.f, 0.f};
    for (int base = wave * 16; base < cnt; base += 64) {
        #pragma unroll
        for (int u = 0; u < 4; ++u) {
            const int p = base + 4 * pos_sub + u;
            if (p < cnt) {
                const float* vp = kv + v_off + (((size_t)s_bt[p >> 4] * BS + (p & 15)) * NH + h) * HD + d4 * 4;
                const float4 v4 = *reinterpret_cast<const float4*>(vp);
                const float w = s_sc[p];
                acc.x += w * v4.x; acc.y += w * v4.y;
                acc.z += w * v4.z; acc.w += w * v4.w;
            }
        }
    }
    acc.x += __shfl_xor(acc.x, 16); acc.y += __shfl_xor(acc.y, 16);
    acc.z += __shfl_xor(acc.z, 16); acc.w += __shfl_xor(acc.w, 16);
    acc.x += __shfl_xor(acc.x, 32); acc.y += __shfl_xor(acc.y, 32);
    acc.z += __shfl_xor(acc.z, 32); acc.w += __shfl_xor(acc.w, 32);
    if (pos_sub == 0) {
        s_part[wave * HD + d4 * 4 + 0] = acc.x;
        s_part[wave * HD + d4 * 4 + 1] = acc.y;
        s_part[wave * HD + d4 * 4 + 2] = acc.z;
        s_part[wave * HD + d4 * 4 + 3] = acc.w;
    }
    __syncthreads();
    if (tid < HD) {
        my_part[tid] = s_part[tid] + s_part[HD + tid] +
                       s_part[2 * HD + tid] + s_part[3 * HD + tid];
    }
    if (tid == 0) { my_part[HD] = m; my_part[HD + 1] = l_tot; }
}

// ---------------------------------------------------------------------------
// Combine split partials over the valid splits only.
// grid (NH, BATCH) x 64.
// ---------------------------------------------------------------------------
__global__ __launch_bounds__(64) void attn_reduce_kernel(
    const float* __restrict__ part,        // [B, NH, SPLITS, HD+2]
    const int* __restrict__ seq_lens,
    float* __restrict__ attn_out)          // [B, HID]
{
    const int h = blockIdx.x, b = blockIdx.y, d = threadIdx.x;
    const int n = seq_lens[b];
    const int ns = (n + CHUNK - 1) / CHUNK;
    const float* pp = part + (size_t)(b * NH + h) * SPLITS * (HD + 2);
    float m = -1e30f;
    for (int s = 0; s < ns; ++s) m = fmaxf(m, pp[s * (HD + 2) + HD]);
    float o = 0.f, l = 0.f;
    for (int s = 0; s < ns; ++s) {
        const float a = __expf(pp[s * (HD + 2) + HD] - m);
        o += a * pp[s * (HD + 2) + d];
        l += a * pp[s * (HD + 2) + HD + 1];
    }
    attn_out[(size_t)b * HID + h * HD + d] = o / l;
}

extern "C" void kernel_launch(void* const* d_in, const int* in_sizes, int n_in,
                              void* d_out, int out_size, void* d_ws, size_t ws_size,
                              hipStream_t stream) {
    const float* hs     = (const float*)d_in[0];
    const float* kv     = (const float*)d_in[1];
    const int*   bt     = (const int*)d_in[2];
    const int*   sl     = (const int*)d_in[3];
    const float* w_attn = (const float*)d_in[4];
    const float* b_attn = (const float*)d_in[5];
    const float* w_proj = (const float*)d_in[6];
    const float* b_proj = (const float*)d_in[7];
    float* out = (float*)d_out;

    float* q    = (float*)d_ws;                        // [B, HID]
    float* attn = q + BATCH * HID;                     // [B, HID]
    float* part = attn + BATCH * HID;                  // [B, NH, SPLITS, HD+2]

    init_kernel<<<BATCH * HID / 256, 256, 0, stream>>>(b_attn, b_proj, q, out);
    gemv_kernel<<<dim3(HID / 64, KSPLIT), 256, 0, stream>>>(hs, w_attn, q, 3 * HID);
    attn_split_kernel<<<dim3(NH, BATCH, SPLITS), 256, 0, stream>>>(q, kv, bt, sl, part);
    attn_reduce_kernel<<<dim3(NH, BATCH), 64, 0, stream>>>(part, sl, attn);
    gemv_kernel<<<dim3(HID / 64, KSPLIT), 256, 0, stream>>>(attn, w_proj, out, HID);
}

// Round 4
// 673.774 us; speedup vs baseline: 1.2817x; 1.0263x over previous
//
#include <hip/hip_runtime.h>
#include <hip/hip_bf16.h>

// Problem constants (from reference)
#define BATCH 32
#define HID 1024
#define NH 16
#define HD 64
#define BS 16
#define MAX_KV 2048
#define BPS 128            // blocks per seq
#define NUM_BLOCKS 4096
#define SCALE 0.125f       // HD^-0.5

#define SPLITS 16
#define CHUNK 128          // MAX_KV / SPLITS
#define KSPLIT 16
#define KCHUNK (HID / KSPLIT)   // 64

// ---------------------------------------------------------------------------
// Init: write biases into q and out (harness poisons ws/out before each run).
// ---------------------------------------------------------------------------
__global__ __launch_bounds__(256) void init_kernel(
    const float* __restrict__ b_attn, const float* __restrict__ b_proj,
    float* __restrict__ q, float* __restrict__ out)
{
    const int i = blockIdx.x * 256 + threadIdx.x;   // [0, 32*1024)
    const int col = i & (HID - 1);
    q[i]   = b_attn[col];   // q slice of c_attn bias
    out[i] = b_proj[col];
}

// ---------------------------------------------------------------------------
// Batched GEMV: y[b, col] += sum_{k in kz-slice} x[b,k] * w[k, col]
// grid (16 col groups, 16 k slices) x 256. Wave w owns batches 8w..8w+7;
// each lane owns one column, 8 batch accumulators; one atomicAdd per (b,col).
// ---------------------------------------------------------------------------
__global__ __launch_bounds__(256) void gemv_kernel(
    const float* __restrict__ x,   // [BATCH, HID]
    const float* __restrict__ w,   // [HID, wstride]
    float* __restrict__ y,         // [BATCH, HID]
    int wstride)
{
    const int colg = blockIdx.x;
    const int kz = blockIdx.y;
    const int tid = threadIdx.x, wave = tid >> 6, lane = tid & 63;
    const int col = colg * 64 + lane;

    __shared__ __align__(16) float s_x[BATCH * KCHUNK];   // 8 KB, [b][k]
    for (int i = tid; i < BATCH * KCHUNK; i += 256) {
        const int bb = i >> 6, kk = i & (KCHUNK - 1);
        s_x[i] = x[bb * HID + kz * KCHUNK + kk];
    }
    __syncthreads();

    const int b0 = wave * 8;
    float acc[8];
    #pragma unroll
    for (int b = 0; b < 8; ++b) acc[b] = 0.f;

    const float4* s_x4 = reinterpret_cast<const float4*>(s_x);
    const float* wp = w + (size_t)(kz * KCHUNK) * wstride + col;
    #pragma unroll
    for (int jb = 0; jb < KCHUNK / 4; ++jb) {
        const float wv0 = wp[(size_t)(jb * 4 + 0) * wstride];
        const float wv1 = wp[(size_t)(jb * 4 + 1) * wstride];
        const float wv2 = wp[(size_t)(jb * 4 + 2) * wstride];
        const float wv3 = wp[(size_t)(jb * 4 + 3) * wstride];
        #pragma unroll
        for (int b = 0; b < 8; ++b) {
            const float4 xv = s_x4[(b0 + b) * (KCHUNK / 4) + jb];
            acc[b] += xv.x * wv0 + xv.y * wv1 + xv.z * wv2 + xv.w * wv3;
        }
    }
    #pragma unroll
    for (int b = 0; b < 8; ++b)
        atomicAdd(&y[(size_t)(b0 + b) * HID + col], acc[b]);
}

// ---------------------------------------------------------------------------
// Single-pass flash-decode split attention. grid (NH, BATCH, SPLITS) x 256.
// Each 16-lane group owns positions; K and V are read together in one pass;
// online softmax with 4 independent (m,l,acc) states per lane for ILP.
// Partial {o[HD], m, l} per (b,h,split) to ws; empty chunks return
// immediately (reduce kernel consults seq_lens).
// ---------------------------------------------------------------------------
__global__ __launch_bounds__(256) void attn_split_kernel(
    const float* __restrict__ q,           // [B, NH, HD]
    const float* __restrict__ kv,          // [2, NUM_BLOCKS, BS, NH, HD]
    const int* __restrict__ block_tables,  // [B, BPS]
    const int* __restrict__ seq_lens,      // [B]
    float* __restrict__ part)              // [B, NH, SPLITS, HD+2]
{
    const int h = blockIdx.x, b = blockIdx.y, s = blockIdx.z;
    const int n = seq_lens[b];
    const int p0 = s * CHUNK;
    if (p0 >= n) return;
    const int cnt = min(n - p0, CHUNK);

    const int tid = threadIdx.x, wave = tid >> 6, lane = tid & 63;
    const int pos_sub = lane >> 4;   // 0..3
    const int d4 = lane & 15;        // 0..15

    float* my_part = part + ((size_t)(b * NH + h) * SPLITS + s) * (HD + 2);

    __shared__ int   s_bt[CHUNK / BS];
    __shared__ float s_m[4], s_l[4];
    __shared__ float s_o[4 * HD];

    if (tid < CHUNK / BS) s_bt[tid] = block_tables[b * BPS + s * (CHUNK / BS) + tid];
    float4 qv = *reinterpret_cast<const float4*>(
        q + (size_t)(b * NH + h) * HD + d4 * 4);
    qv.x *= SCALE; qv.y *= SCALE; qv.z *= SCALE; qv.w *= SCALE;
    __syncthreads();

    const size_t v_off = (size_t)NUM_BLOCKS * BS * NH * HD;

    // 4 independent online-softmax states per lane
    float m[4], l[4];
    float4 acc[4];
    #pragma unroll
    for (int u = 0; u < 4; ++u) {
        m[u] = -1e30f; l[u] = 0.f;
        acc[u].x = acc[u].y = acc[u].z = acc[u].w = 0.f;
    }

    for (int base = wave * 16; base < cnt; base += 64) {
        float sc[4];
        float4 vv[4];
        // issue all K+V loads first (8 KB in flight per wave)
        #pragma unroll
        for (int u = 0; u < 4; ++u) {
            const int p = base + pos_sub * 4 + u;
            sc[u] = 0.f;
            vv[u].x = vv[u].y = vv[u].z = vv[u].w = 0.f;
            if (p < cnt) {
                const size_t boff = (((size_t)s_bt[p >> 4] * BS + (p & 15)) * NH + h) * HD + d4 * 4;
                const float4 k4 = *reinterpret_cast<const float4*>(kv + boff);
                vv[u] = *reinterpret_cast<const float4*>(kv + v_off + boff);
                sc[u] = qv.x * k4.x + qv.y * k4.y + qv.z * k4.z + qv.w * k4.w;
            }
        }
        // score reduction across the 16 d4 lanes
        #pragma unroll
        for (int u = 0; u < 4; ++u) {
            sc[u] += __shfl_xor(sc[u], 1);
            sc[u] += __shfl_xor(sc[u], 2);
            sc[u] += __shfl_xor(sc[u], 4);
            sc[u] += __shfl_xor(sc[u], 8);
        }
        // online-softmax update, independent per u
        #pragma unroll
        for (int u = 0; u < 4; ++u) {
            const int p = base + pos_sub * 4 + u;
            if (p < cnt) {
                const float mn = fmaxf(m[u], sc[u]);
                const float sca = __expf(m[u] - mn);
                const float f   = __expf(sc[u] - mn);
                l[u] = l[u] * sca + f;
                acc[u].x = acc[u].x * sca + f * vv[u].x;
                acc[u].y = acc[u].y * sca + f * vv[u].y;
                acc[u].z = acc[u].z * sca + f * vv[u].z;
                acc[u].w = acc[u].w * sca + f * vv[u].w;
                m[u] = mn;
            }
        }
    }

    // ---- merge the 4 u-states (per lane) ----
    float mm = fmaxf(fmaxf(m[0], m[1]), fmaxf(m[2], m[3]));
    const float a0 = __expf(m[0] - mm), a1 = __expf(m[1] - mm);
    const float a2 = __expf(m[2] - mm), a3 = __expf(m[3] - mm);
    float ll = l[0] * a0 + l[1] * a1 + l[2] * a2 + l[3] * a3;
    float4 oo;
    oo.x = acc[0].x * a0 + acc[1].x * a1 + acc[2].x * a2 + acc[3].x * a3;
    oo.y = acc[0].y * a0 + acc[1].y * a1 + acc[2].y * a2 + acc[3].y * a3;
    oo.z = acc[0].z * a0 + acc[1].z * a1 + acc[2].z * a2 + acc[3].z * a3;
    oo.w = acc[0].w * a0 + acc[1].w * a1 + acc[2].w * a2 + acc[3].w * a3;

    // ---- merge across the 4 lane-groups (xor 16, 32) ----
    #pragma unroll
    for (int msk = 16; msk <= 32; msk <<= 1) {
        const float mo = __shfl_xor(mm, msk);
        const float lo = __shfl_xor(ll, msk);
        float4 ot;
        ot.x = __shfl_xor(oo.x, msk); ot.y = __shfl_xor(oo.y, msk);
        ot.z = __shfl_xor(oo.z, msk); ot.w = __shfl_xor(oo.w, msk);
        const float mn = fmaxf(mm, mo);
        const float sa = __expf(mm - mn), sb = __expf(mo - mn);
        ll = ll * sa + lo * sb;
        oo.x = oo.x * sa + ot.x * sb; oo.y = oo.y * sa + ot.y * sb;
        oo.z = oo.z * sa + ot.z * sb; oo.w = oo.w * sa + ot.w * sb;
        mm = mn;
    }

    // ---- merge across the 4 waves via LDS ----
    if (pos_sub == 0) {
        s_o[wave * HD + d4 * 4 + 0] = oo.x;
        s_o[wave * HD + d4 * 4 + 1] = oo.y;
        s_o[wave * HD + d4 * 4 + 2] = oo.z;
        s_o[wave * HD + d4 * 4 + 3] = oo.w;
        if (d4 == 0) { s_m[wave] = mm; s_l[wave] = ll; }
    }
    __syncthreads();
    if (tid < HD) {
        const float M = fmaxf(fmaxf(s_m[0], s_m[1]), fmaxf(s_m[2], s_m[3]));
        const float w0 = __expf(s_m[0] - M), w1 = __expf(s_m[1] - M);
        const float w2 = __expf(s_m[2] - M), w3 = __expf(s_m[3] - M);
        my_part[tid] = s_o[tid] * w0 + s_o[HD + tid] * w1 +
                       s_o[2 * HD + tid] * w2 + s_o[3 * HD + tid] * w3;
        if (tid == 0) {
            my_part[HD] = M;
            my_part[HD + 1] = s_l[0] * w0 + s_l[1] * w1 + s_l[2] * w2 + s_l[3] * w3;
        }
    }
}

// ---------------------------------------------------------------------------
// Combine split partials over the valid splits only. grid (NH, BATCH) x 64.
// ---------------------------------------------------------------------------
__global__ __launch_bounds__(64) void attn_reduce_kernel(
    const float* __restrict__ part,        // [B, NH, SPLITS, HD+2]
    const int* __restrict__ seq_lens,
    float* __restrict__ attn_out)          // [B, HID]
{
    const int h = blockIdx.x, b = blockIdx.y, d = threadIdx.x;
    const int n = seq_lens[b];
    const int ns = (n + CHUNK - 1) / CHUNK;
    const float* pp = part + (size_t)(b * NH + h) * SPLITS * (HD + 2);
    float m = -1e30f;
    for (int s = 0; s < ns; ++s) m = fmaxf(m, pp[s * (HD + 2) + HD]);
    float o = 0.f, l = 0.f;
    for (int s = 0; s < ns; ++s) {
        const float a = __expf(pp[s * (HD + 2) + HD] - m);
        o += a * pp[s * (HD + 2) + d];
        l += a * pp[s * (HD + 2) + HD + 1];
    }
    attn_out[(size_t)b * HID + h * HD + d] = o / l;
}

extern "C" void kernel_launch(void* const* d_in, const int* in_sizes, int n_in,
                              void* d_out, int out_size, void* d_ws, size_t ws_size,
                              hipStream_t stream) {
    const float* hs     = (const float*)d_in[0];
    const float* kv     = (const float*)d_in[1];
    const int*   bt     = (const int*)d_in[2];
    const int*   sl     = (const int*)d_in[3];
    const float* w_attn = (const float*)d_in[4];
    const float* b_attn = (const float*)d_in[5];
    const float* w_proj = (const float*)d_in[6];
    const float* b_proj = (const float*)d_in[7];
    float* out = (float*)d_out;

    float* q    = (float*)d_ws;                        // [B, HID]
    float* attn = q + BATCH * HID;                     // [B, HID]
    float* part = attn + BATCH * HID;                  // [B, NH, SPLITS, HD+2]

    init_kernel<<<BATCH * HID / 256, 256, 0, stream>>>(b_attn, b_proj, q, out);
    gemv_kernel<<<dim3(HID / 64, KSPLIT), 256, 0, stream>>>(hs, w_attn, q, 3 * HID);
    attn_split_kernel<<<dim3(NH, BATCH, SPLITS), 256, 0, stream>>>(q, kv, bt, sl, part);
    attn_reduce_kernel<<<dim3(NH, BATCH), 64, 0, stream>>>(part, sl, attn);
    gemv_kernel<<<dim3(HID / 64, KSPLIT), 256, 0, stream>>>(attn, w_proj, out, HID);
}